// Round 15
// baseline (263.548 us; speedup 1.0000x reference)
//
#include <hip/hip_runtime.h>
#include <math.h>

typedef float f32x4 __attribute__((ext_vector_type(4)));
typedef short s16x8 __attribute__((ext_vector_type(8)));

__device__ __forceinline__ unsigned short f2bf(float f) {
    unsigned u = __builtin_bit_cast(unsigned, f);
    u += 0x7fffu + ((u >> 16) & 1u);
    return (unsigned short)(u >> 16);
}

// Pack 4 f32 -> 4 bf16 (round-half-up) via v_perm_b32 (builtin, no asm).
__device__ __forceinline__ uint2 pack4(float q0, float q1, float q2, float q3) {
    unsigned u0 = __builtin_bit_cast(unsigned, q0) + 0x8000u;
    unsigned u1 = __builtin_bit_cast(unsigned, q1) + 0x8000u;
    unsigned u2 = __builtin_bit_cast(unsigned, q2) + 0x8000u;
    unsigned u3 = __builtin_bit_cast(unsigned, q3) + 0x8000u;
    uint2 r;
    r.x = __builtin_amdgcn_perm(u1, u0, 0x07060302);
    r.y = __builtin_amdgcn_perm(u3, u2, 0x07060302);
    return r;
}

// Bijective XCD-chunking swizzle (kept; harmless).
__device__ __forceinline__ int xcd_swizzle(int b, int nwg) {
    int q = nwg >> 3, r = nwg & 7;
    int xcd = b & 7, slot = b >> 3;
    int base = (xcd < r) ? xcd * (q + 1) : r * (q + 1) + (xcd - r) * q;
    return base + slot;
}

// ---------------- weight packing (+ fused counts zeroing) ----------------
// Frag (kt,nt): lane l elem j holds W[16nt+(l&15)][32kt+8*(l>>4)+j].
#define PACK_TOT 36864

__global__ __launch_bounds__(256) void pack_weights_k(
    const float* __restrict__ w0, const float* __restrict__ w1,
    const float* __restrict__ w2, const float* __restrict__ w3,
    const float* __restrict__ wv, unsigned short* __restrict__ dst,
    int* __restrict__ counts, int N)
{
    int idx = blockIdx.x * 256 + threadIdx.x;
    int stride = gridDim.x * 256;
    for (int i = idx; i < N; i += stride) counts[i] = 0;   // replaces memset(counts)
    if (idx >= PACK_TOT) return;
    const float* W; int inF, ntiles, off;
    if (idx < 3072)       { W = w0; inF = 8;  ntiles = 6; off = 0; }
    else if (idx < 12288) { W = w1; inF = 96; ntiles = 6; off = 3072; }
    else if (idx < 21504) { W = w2; inF = 96; ntiles = 6; off = 12288; }
    else if (idx < 30720) { W = w3; inF = 96; ntiles = 6; off = 21504; }
    else                  { W = wv; inF = 96; ntiles = 4; off = 30720; }
    int r  = idx - off;
    int fi = r >> 9;
    int wi = r & 511;
    int l = wi >> 3, j = wi & 7;
    int kt = fi / ntiles, nt = fi - kt * ntiles;
    int n = nt * 16 + (l & 15);
    int k = kt * 32 + ((l >> 4) << 3) + j;
    float v = (k < inF) ? W[n * inF + k] : 0.0f;
    dst[idx] = f2bf(v);
}

// ---------------- CSR build (+ fused d_out zeroing) ----------------
__global__ __launch_bounds__(256) void hist_k(const int* __restrict__ src,
                                              int* __restrict__ counts,
                                              float4* __restrict__ dz, long nz,
                                              int E)
{
    long tid = (long)blockIdx.x * 256 + threadIdx.x;
    long stride = (long)gridDim.x * 256;
    float4 z4 = make_float4(0.f, 0.f, 0.f, 0.f);
    for (long i = tid; i < nz; i += stride) dz[i] = z4;     // replaces memset(d_out)
    int e = blockIdx.x * 256 + threadIdx.x;
    if (e < E) atomicAdd(&counts[src[e]], 1);
}

__global__ __launch_bounds__(256) void scan1_k(const int* __restrict__ counts,
                                               int* __restrict__ cursor,
                                               int* __restrict__ bsum, int N)
{
    __shared__ int wsum_s[4];
    int b = blockIdx.x, t = threadIdx.x, lane = t & 63, wid = t >> 6;
    int i0 = b * 2048 + t * 8;
    int v[8]; int s = 0;
    #pragma unroll
    for (int j = 0; j < 8; j++) { int i = i0 + j; v[j] = (i < N) ? counts[i] : 0; s += v[j]; }
    int inc = s;
    #pragma unroll
    for (int d = 1; d < 64; d <<= 1) { int o = __shfl_up(inc, d, 64); if (lane >= d) inc += o; }
    if (lane == 63) wsum_s[wid] = inc;
    __syncthreads();
    int wb = 0;
    for (int k = 0; k < wid; k++) wb += wsum_s[k];
    int run = wb + inc - s;
    #pragma unroll
    for (int j = 0; j < 8; j++) { int i = i0 + j; if (i < N) cursor[i] = run; run += v[j]; }
    if (t == 255) bsum[b] = wb + inc;
}

// scatter with inline chunk-total prefix; rsrt written non-temporally
__global__ __launch_bounds__(256) void scatter_k(const int* __restrict__ src,
                                                 const float* __restrict__ r_ij,
                                                 const int* __restrict__ bsum,
                                                 int* __restrict__ cursor,
                                                 int* __restrict__ order,
                                                 int* __restrict__ srcs,
                                                 float4* __restrict__ rsrt,
                                                 int use_rsrt, int nb, int E)
{
    __shared__ int pre_s[256];
    int t = threadIdx.x;
    if (t < 64) {
        int carry = 0;
        for (int base = 0; base < nb; base += 64) {
            int i = base + t;
            int v = (i < nb) ? bsum[i] : 0;
            int inc = v;
            #pragma unroll
            for (int d = 1; d < 64; d <<= 1) {
                int o = __shfl_up(inc, d, 64);
                if (t >= d) inc += o;
            }
            if (i < nb) pre_s[i] = carry + inc - v;
            carry += __shfl(inc, 63);
        }
    }
    __syncthreads();
    int e = blockIdx.x * 256 + t;
    if (e < E) {
        int s = src[e];
        int p = pre_s[s >> 11] + atomicAdd(&cursor[s], 1);
        if (use_rsrt) {
            f32x4 v4 = {r_ij[3*e], r_ij[3*e+1], r_ij[3*e+2], __int_as_float(s)};
            __builtin_nontemporal_store(v4, (f32x4*)&rsrt[p]);
        } else {
            order[p] = e;
            srcs[p] = s;
        }
    }
}

// ---------------- fused edge kernel ----------------
// r14 body at 4 blocks/CU: r9's 4/CU regression was L2 capacity thrash from
// the ALL-atomic RMW working set; r14's NT interior stores (~78% of writes,
// no L2 allocation) shrink that footprint ~4x, so retry the occupancy.
__global__ __launch_bounds__(256, 4) void edge_kernel(
    const float* __restrict__ r_ij,
    const int* __restrict__ order, const int* __restrict__ srcs,
    const float4* __restrict__ rsrt, int use_rsrt,
    const unsigned short* __restrict__ wp,
    const float* __restrict__ b0, const float* __restrict__ b1, const float* __restrict__ b2,
    float* __restrict__ A_a, float* __restrict__ Ov, int E)
{
    __shared__ unsigned short h_s[16896];
    __shared__ unsigned short rvb_s[3 * 128];      // bf16 rv, [c][row]
    __shared__ unsigned char  segid_s[128];
    __shared__ int  segnode_s[128];
    __shared__ int  src_s[128];
    __shared__ int  nseg_s;

    const int tid = threadIdx.x;
    const int w  = tid >> 6;
    const int l  = tid & 63;
    const int e0 = xcd_swizzle(blockIdx.x, gridDim.x) * 128;
    const int lr = l & 15;
    const int lg = l >> 4;
    const int mbase = w * 32;

    // ---- stage per-edge scalars
    if (l < 32) {
        const int ml = mbase + l;
        const int pos = e0 + ml;
        float x = 0.f, y = 0.f, z = 0.f; int s = -1;
        if (pos < E) {
            if (use_rsrt) {
                f32x4 t4 = __builtin_nontemporal_load((const f32x4*)&rsrt[pos]);
                x = t4[0]; y = t4[1]; z = t4[2]; s = __float_as_int(t4[3]);
            } else {
                int e = order[pos];
                s = srcs[pos];
                x = r_ij[3*e]; y = r_ij[3*e+1]; z = r_ij[3*e+2];
            }
        }
        float r = sqrtf(x*x + y*y + z*z);
        float u = r * 4.0f;               // r * 8/R0, R0=2
        s16x8 ev;
        #pragma unroll
        for (int k = 0; k < 8; k++) {
            float t = fmaxf(1.0f - fabsf(u - (float)k), 0.0f);
            ev[k] = (short)f2bf((s >= 0) ? t : 0.0f);
        }
        *(s16x8*)&h_s[ml * 104 + 96] = ev;     // enc into pad cols
        float nn = 3.5f * r;
        float sc = (s >= 0) ? (3.5f * tanhf(nn) / fmaxf(nn, 1e-12f)) : 0.0f;
        rvb_s[0*128 + ml] = f2bf(x * sc);
        rvb_s[1*128 + ml] = f2bf(y * sc);
        rvb_s[2*128 + ml] = f2bf(z * sc);
        src_s[ml] = s;
    }
    __syncthreads();   // SYNC#1: src_s/enc visible

    // ---- wave 0: build segid / segnode / nseg (ballot-based prefix)
    if (w == 0) {
        int i = l;
        int sA = src_s[i];
        bool fA = (i == 0) || (sA != src_s[i - 1]);
        unsigned long long mA = __ballot(fA);
        unsigned long long maskA = (~0ull) >> (63 - i);
        int incA = (int)__popcll(mA & maskA);
        segid_s[i] = (unsigned char)(incA - 1);
        if (fA) segnode_s[incA - 1] = sA;
        int totA = (int)__popcll(mA);
        int jrow = 64 + i;
        int sB = src_s[jrow];
        bool fB = (sB != src_s[jrow - 1]);
        unsigned long long mB = __ballot(fB);
        int incB = (int)__popcll(mB & maskA);
        segid_s[jrow] = (unsigned char)(totA + incB - 1);
        if (fB) segnode_s[totA + incB - 1] = sB;
        if (i == 63) nseg_s = totA + (int)__popcll(mB);
    }

    // ---- biases as float4 per (nt, lg): feat = nt*16 + lg*4 + jj (swapped D)
    f32x4 b0v4[6], b1v4[6], b2v4[6];
    #pragma unroll
    for (int nt = 0; nt < 6; nt++) {
        float4 t0 = *(const float4*)&b0[nt*16 + lg*4];
        float4 t1 = *(const float4*)&b1[nt*16 + lg*4];
        float4 t2 = *(const float4*)&b2[nt*16 + lg*4];
        b0v4[nt] = (f32x4){t0.x, t0.y, t0.z, t0.w};
        b1v4[nt] = (f32x4){t1.x, t1.y, t1.z, t1.w};
        b2v4[nt] = (f32x4){t2.x, t2.y, t2.z, t2.w};
    }

    // ---- layer 0 (swapped): D[feat][edge] = w0_frag x enc_frag + b0
    {
        s16x8 hb[2];
        #pragma unroll
        for (int mf = 0; mf < 2; mf++) {
            s16x8 a = {0,0,0,0,0,0,0,0};
            if (l < 16) a = *(const s16x8*)&h_s[(mbase + mf*16 + lr) * 104 + 96];
            hb[mf] = a;
        }
        f32x4 acc[2][6];
        #pragma unroll
        for (int nt = 0; nt < 6; nt++) {
            s16x8 Wf = *(const s16x8*)&wp[nt * 512 + l * 8];
            acc[0][nt] = __builtin_amdgcn_mfma_f32_16x16x32_bf16(Wf, hb[0], b0v4[nt], 0, 0, 0);
            acc[1][nt] = __builtin_amdgcn_mfma_f32_16x16x32_bf16(Wf, hb[1], b0v4[nt], 0, 0, 0);
        }
        #pragma unroll
        for (int mf = 0; mf < 2; mf++)
        #pragma unroll
        for (int nt = 0; nt < 6; nt++)
            *(uint2*)&h_s[(mbase + mf*16 + lr) * 104 + nt*16 + lg*4] =
                pack4(acc[mf][nt][0], acc[mf][nt][1], acc[mf][nt][2], acc[mf][nt][3]);
    }

    // ---- layers 1,2 (swapped): in-place leaky(W x h + b); b64 epilogue
    #pragma unroll
    for (int li = 0; li < 2; li++) {
        const int poff = 3072 + li * 9216;
        s16x8 A[2][3];
        #pragma unroll
        for (int mf = 0; mf < 2; mf++)
        #pragma unroll
        for (int kt = 0; kt < 3; kt++)
            A[mf][kt] = *(const s16x8*)&h_s[(mbase + mf*16 + lr) * 104 + kt*32 + lg*8];
        f32x4 a2[2][6];
        #pragma unroll
        for (int nt = 0; nt < 6; nt++) {
            f32x4 bi = (li == 0) ? b1v4[nt] : b2v4[nt];
            a2[0][nt] = bi; a2[1][nt] = bi;
        }
        #pragma unroll
        for (int nt = 0; nt < 6; nt++)
        #pragma unroll
        for (int kt = 0; kt < 3; kt++) {
            s16x8 Wf = *(const s16x8*)&wp[poff + (kt*6 + nt) * 512 + l * 8];
            a2[0][nt] = __builtin_amdgcn_mfma_f32_16x16x32_bf16(Wf, A[0][kt], a2[0][nt], 0, 0, 0);
            a2[1][nt] = __builtin_amdgcn_mfma_f32_16x16x32_bf16(Wf, A[1][kt], a2[1][nt], 0, 0, 0);
        }
        #pragma unroll
        for (int mf = 0; mf < 2; mf++)
        #pragma unroll
        for (int nt = 0; nt < 6; nt++) {
            float q0 = a2[mf][nt][0], q1 = a2[mf][nt][1];
            float q2 = a2[mf][nt][2], q3 = a2[mf][nt][3];
            q0 = fmaxf(q0, 0.1f*q0); q1 = fmaxf(q1, 0.1f*q1);
            q2 = fmaxf(q2, 0.1f*q2); q3 = fmaxf(q3, 0.1f*q3);
            *(uint2*)&h_s[(mbase + mf*16 + lr) * 104 + nt*16 + lg*4] = pack4(q0, q1, q2, q3);
        }
    }

    // ---- layer 3 (old orientation): rad = h @ w3.T -> packed regs
    uint2 radp[2][6];
    {
        s16x8 A[2][3];
        #pragma unroll
        for (int mf = 0; mf < 2; mf++)
        #pragma unroll
        for (int kt = 0; kt < 3; kt++)
            A[mf][kt] = *(const s16x8*)&h_s[(mbase + mf*16 + lr) * 104 + kt*32 + lg*8];
        f32x4 rad[2][6] = {};
        #pragma unroll
        for (int nt = 0; nt < 6; nt++)
        #pragma unroll
        for (int kt = 0; kt < 3; kt++) {
            s16x8 B = *(const s16x8*)&wp[21504 + (kt*6 + nt) * 512 + l * 8];
            rad[0][nt] = __builtin_amdgcn_mfma_f32_16x16x32_bf16(A[0][kt], B, rad[0][nt], 0, 0, 0);
            rad[1][nt] = __builtin_amdgcn_mfma_f32_16x16x32_bf16(A[1][kt], B, rad[1][nt], 0, 0, 0);
        }
        #pragma unroll
        for (int mf = 0; mf < 2; mf++)
        #pragma unroll
        for (int nt = 0; nt < 6; nt++)
            radp[mf][nt] = pack4(rad[mf][nt][0], rad[mf][nt][1], rad[mf][nt][2], rad[mf][nt][3]);
    }

    __syncthreads();   // SYNC#2: all row-major reads of h done -> overlay allowed

    // ---- rad -> B-fragment-order stash (overlays h_s[0 .. 12288 u16))
    #pragma unroll
    for (int mf = 0; mf < 2; mf++)
    #pragma unroll
    for (int nt = 0; nt < 6; nt++)
        *(uint2*)&h_s[(w*6 + nt) * 512 + ((2*mf + (lg>>1))*16 + lr) * 8 + (lg&1)*4] = radp[mf][nt];

    __syncthreads();   // SYNC#3: rad frags + segid visible

    // ---- segment reduction (interior segs: plain NT store; boundary: atomic)
    const int nseg = nseg_s;
    if (w == 0) {
        for (int st = 0; st * 16 < nseg; ++st) {
            const int target = st * 16 + lr;
            f32x4 acc[6] = {};
            #pragma unroll
            for (int kt = 0; kt < 4; kt++) {
                uint2 sid8 = *(const uint2*)&segid_s[kt*32 + 8*lg];
                s16x8 af;
                #pragma unroll
                for (int j = 0; j < 8; j++) {
                    unsigned word = (j < 4) ? sid8.x : sid8.y;
                    int sid = (word >> (8 * (j & 3))) & 255;
                    af[j] = (short)((sid == target) ? 0x3F80 : 0);
                }
                #pragma unroll
                for (int nt = 0; nt < 6; nt++) {
                    s16x8 B = *(const s16x8*)&h_s[(kt*6 + nt) * 512 + l * 8];
                    acc[nt] = __builtin_amdgcn_mfma_f32_16x16x32_bf16(af, B, acc[nt], 0, 0, 0);
                }
            }
            #pragma unroll
            for (int nt = 0; nt < 6; nt++)
            #pragma unroll
            for (int j = 0; j < 4; j++) {
                int g = st*16 + 4*lg + j;
                if (g < nseg) {
                    int node = segnode_s[g];
                    if (node >= 0) {
                        float* p = &A_a[node*96 + nt*16 + lr];
                        if (g == 0 || g == nseg - 1) unsafeAtomicAdd(p, acc[nt][j]);
                        else __builtin_nontemporal_store(acc[nt][j], p);
                    }
                }
            }
        }
    } else {
        const int c = w - 1;
        const int scb = 12288 + (w - 1) * 1536;
        for (int st = 0; st * 16 < nseg; ++st) {
            const int target = st * 16 + lr;
            f32x4 acc6[6] = {};
            #pragma unroll
            for (int kt = 0; kt < 4; kt++) {
                uint2 sid8 = *(const uint2*)&segid_s[kt*32 + 8*lg];
                s16x8 rv8 = *(const s16x8*)&rvb_s[c*128 + kt*32 + 8*lg];
                s16x8 af;
                #pragma unroll
                for (int j = 0; j < 8; j++) {
                    unsigned word = (j < 4) ? sid8.x : sid8.y;
                    int sid = (word >> (8 * (j & 3))) & 255;
                    af[j] = (sid == target) ? rv8[j] : (short)0;
                }
                #pragma unroll
                for (int nt = 0; nt < 6; nt++) {
                    s16x8 B = *(const s16x8*)&h_s[(kt*6 + nt) * 512 + l * 8];
                    acc6[nt] = __builtin_amdgcn_mfma_f32_16x16x32_bf16(af, B, acc6[nt], 0, 0, 0);
                }
            }
            #pragma unroll
            for (int nt = 0; nt < 6; nt++) {
                int ktf = nt >> 1;
                int lane2 = ((nt & 1) * 2 + (lr >> 3)) * 16 + 4*lg;
                int a0 = scb + ktf*512 + lane2*8 + (lr & 7);
                h_s[a0]      = f2bf(acc6[nt][0]);
                h_s[a0 + 8]  = f2bf(acc6[nt][1]);
                h_s[a0 + 16] = f2bf(acc6[nt][2]);
                h_s[a0 + 24] = f2bf(acc6[nt][3]);
            }
            s16x8 As[3];
            #pragma unroll
            for (int ktf = 0; ktf < 3; ktf++)
                As[ktf] = *(const s16x8*)&h_s[scb + ktf*512 + l*8];
            f32x4 acc2[4] = {};
            #pragma unroll
            for (int vt = 0; vt < 4; vt++)
            #pragma unroll
            for (int ktf = 0; ktf < 3; ktf++) {
                s16x8 B = *(const s16x8*)&wp[30720 + (ktf*4 + vt) * 512 + l * 8];
                acc2[vt] = __builtin_amdgcn_mfma_f32_16x16x32_bf16(As[ktf], B, acc2[vt], 0, 0, 0);
            }
            #pragma unroll
            for (int vt = 0; vt < 4; vt++)
            #pragma unroll
            for (int j = 0; j < 4; j++) {
                int g = st*16 + 4*lg + j;
                if (g < nseg) {
                    int node = segnode_s[g];
                    if (node >= 0) {
                        float* p = &Ov[node*192 + (vt*16 + lr)*3 + c];
                        if (g == 0 || g == nseg - 1) unsafeAtomicAdd(p, acc2[vt][j]);
                        else __builtin_nontemporal_store(acc2[vt][j], p);
                    }
                }
            }
        }
    }
}

extern "C" void kernel_launch(void* const* d_in, const int* in_sizes, int n_in,
                              void* d_out, int out_size, void* d_ws, size_t ws_size,
                              hipStream_t stream)
{
    const float* r_ij = (const float*)d_in[0];
    const float* w0   = (const float*)d_in[1];
    const float* b0   = (const float*)d_in[2];
    const float* w1   = (const float*)d_in[3];
    const float* b1   = (const float*)d_in[4];
    const float* w2   = (const float*)d_in[5];
    const float* b2   = (const float*)d_in[6];
    const float* w3   = (const float*)d_in[7];
    const float* wv   = (const float*)d_in[8];
    const int*   src  = (const int*)d_in[9];
    const int E = in_sizes[0] / 3;
    const int N = out_size / 288;
    float* A_a = (float*)d_out;
    float* Ov  = A_a + (size_t)N * 96;

    char* wsb = (char*)d_ws;
    unsigned short* wp = (unsigned short*)wsb;                  // 73728 B
    size_t off = 73728;
    int* counts = (int*)(wsb + off);  off += (((size_t)N*4 + 127) & ~127ull);
    int* cursor = (int*)(wsb + off);  off += (((size_t)N*4 + 127) & ~127ull);
    int* bsum   = (int*)(wsb + off);  off += 1024;
    size_t need_rsrt = off + (size_t)E * 16;
    int use_rsrt = (need_rsrt <= ws_size) ? 1 : 0;
    float4* rsrt = (float4*)(wsb + off);
    int* order   = (int*)(wsb + off);
    int* srcs    = (int*)(wsb + off + (((size_t)E*4 + 127) & ~127ull));

    const int nb = (N + 2047) / 2048;
    const long nz = (long)out_size / 4;     // out_size = 288*N, divisible by 4

    pack_weights_k<<<(PACK_TOT + 255) / 256, 256, 0, stream>>>(w0, w1, w2, w3, wv, wp,
                                                               counts, N);
    hist_k<<<(E + 255) / 256, 256, 0, stream>>>(src, counts, (float4*)d_out, nz, E);
    scan1_k<<<nb, 256, 0, stream>>>(counts, cursor, bsum, N);
    scatter_k<<<(E + 255) / 256, 256, 0, stream>>>(src, r_ij, bsum, cursor,
                                                   order, srcs, rsrt, use_rsrt, nb, E);
    edge_kernel<<<(E + 127) / 128, 256, 0, stream>>>(r_ij, order, srcs, rsrt, use_rsrt,
                                                     wp, b0, b1, b2, A_a, Ov, E);
}

// Round 16
// 242.169 us; speedup vs baseline: 1.0883x; 1.0883x over previous
//
#include <hip/hip_runtime.h>
#include <math.h>

typedef float f32x4 __attribute__((ext_vector_type(4)));
typedef short s16x8 __attribute__((ext_vector_type(8)));

__device__ __forceinline__ unsigned short f2bf(float f) {
    unsigned u = __builtin_bit_cast(unsigned, f);
    u += 0x7fffu + ((u >> 16) & 1u);
    return (unsigned short)(u >> 16);
}

// Pack 4 f32 -> 4 bf16 (round-half-up) via v_perm_b32 (builtin, no asm).
__device__ __forceinline__ uint2 pack4(float q0, float q1, float q2, float q3) {
    unsigned u0 = __builtin_bit_cast(unsigned, q0) + 0x8000u;
    unsigned u1 = __builtin_bit_cast(unsigned, q1) + 0x8000u;
    unsigned u2 = __builtin_bit_cast(unsigned, q2) + 0x8000u;
    unsigned u3 = __builtin_bit_cast(unsigned, q3) + 0x8000u;
    uint2 r;
    r.x = __builtin_amdgcn_perm(u1, u0, 0x07060302);
    r.y = __builtin_amdgcn_perm(u3, u2, 0x07060302);
    return r;
}

// Bijective XCD-chunking swizzle (kept; harmless).
__device__ __forceinline__ int xcd_swizzle(int b, int nwg) {
    int q = nwg >> 3, r = nwg & 7;
    int xcd = b & 7, slot = b >> 3;
    int base = (xcd < r) ? xcd * (q + 1) : r * (q + 1) + (xcd - r) * q;
    return base + slot;
}

// ---------------- weight packing (+ fused counts zeroing) ----------------
// Frag (kt,nt): lane l elem j holds W[16nt+(l&15)][32kt+8*(l>>4)+j].
#define PACK_TOT 36864

__global__ __launch_bounds__(256) void pack_weights_k(
    const float* __restrict__ w0, const float* __restrict__ w1,
    const float* __restrict__ w2, const float* __restrict__ w3,
    const float* __restrict__ wv, unsigned short* __restrict__ dst,
    int* __restrict__ counts, int N)
{
    int idx = blockIdx.x * 256 + threadIdx.x;
    int stride = gridDim.x * 256;
    for (int i = idx; i < N; i += stride) counts[i] = 0;   // replaces memset(counts)
    if (idx >= PACK_TOT) return;
    const float* W; int inF, ntiles, off;
    if (idx < 3072)       { W = w0; inF = 8;  ntiles = 6; off = 0; }
    else if (idx < 12288) { W = w1; inF = 96; ntiles = 6; off = 3072; }
    else if (idx < 21504) { W = w2; inF = 96; ntiles = 6; off = 12288; }
    else if (idx < 30720) { W = w3; inF = 96; ntiles = 6; off = 21504; }
    else                  { W = wv; inF = 96; ntiles = 4; off = 30720; }
    int r  = idx - off;
    int fi = r >> 9;
    int wi = r & 511;
    int l = wi >> 3, j = wi & 7;
    int kt = fi / ntiles, nt = fi - kt * ntiles;
    int n = nt * 16 + (l & 15);
    int k = kt * 32 + ((l >> 4) << 3) + j;
    float v = (k < inF) ? W[n * inF + k] : 0.0f;
    dst[idx] = f2bf(v);
}

// ---------------- CSR build (+ fused NT d_out zeroing) ----------------
__global__ __launch_bounds__(256) void hist_k(const int* __restrict__ src,
                                              int* __restrict__ counts,
                                              float4* __restrict__ dz, long nz,
                                              int E)
{
    long tid = (long)blockIdx.x * 256 + threadIdx.x;
    long stride = (long)gridDim.x * 256;
    f32x4 z4 = {0.f, 0.f, 0.f, 0.f};
    for (long i = tid; i < nz; i += stride)
        __builtin_nontemporal_store(z4, (f32x4*)&dz[i]);    // NT: keep L2 clean
    int e = blockIdx.x * 256 + threadIdx.x;
    if (e < E) atomicAdd(&counts[src[e]], 1);
}

__global__ __launch_bounds__(256) void scan1_k(const int* __restrict__ counts,
                                               int* __restrict__ cursor,
                                               int* __restrict__ bsum, int N)
{
    __shared__ int wsum_s[4];
    int b = blockIdx.x, t = threadIdx.x, lane = t & 63, wid = t >> 6;
    int i0 = b * 2048 + t * 8;
    int v[8]; int s = 0;
    #pragma unroll
    for (int j = 0; j < 8; j++) { int i = i0 + j; v[j] = (i < N) ? counts[i] : 0; s += v[j]; }
    int inc = s;
    #pragma unroll
    for (int d = 1; d < 64; d <<= 1) { int o = __shfl_up(inc, d, 64); if (lane >= d) inc += o; }
    if (lane == 63) wsum_s[wid] = inc;
    __syncthreads();
    int wb = 0;
    for (int k = 0; k < wid; k++) wb += wsum_s[k];
    int run = wb + inc - s;
    #pragma unroll
    for (int j = 0; j < 8; j++) { int i = i0 + j; if (i < N) cursor[i] = run; run += v[j]; }
    if (t == 255) bsum[b] = wb + inc;
}

// scatter with inline chunk-total prefix; rsrt written non-temporally
__global__ __launch_bounds__(256) void scatter_k(const int* __restrict__ src,
                                                 const float* __restrict__ r_ij,
                                                 const int* __restrict__ bsum,
                                                 int* __restrict__ cursor,
                                                 int* __restrict__ order,
                                                 int* __restrict__ srcs,
                                                 float4* __restrict__ rsrt,
                                                 int use_rsrt, int nb, int E)
{
    __shared__ int pre_s[256];
    int t = threadIdx.x;
    if (t < 64) {
        int carry = 0;
        for (int base = 0; base < nb; base += 64) {
            int i = base + t;
            int v = (i < nb) ? bsum[i] : 0;
            int inc = v;
            #pragma unroll
            for (int d = 1; d < 64; d <<= 1) {
                int o = __shfl_up(inc, d, 64);
                if (t >= d) inc += o;
            }
            if (i < nb) pre_s[i] = carry + inc - v;
            carry += __shfl(inc, 63);
        }
    }
    __syncthreads();
    int e = blockIdx.x * 256 + t;
    if (e < E) {
        int s = src[e];
        int p = pre_s[s >> 11] + atomicAdd(&cursor[s], 1);
        if (use_rsrt) {
            f32x4 v4 = {r_ij[3*e], r_ij[3*e+1], r_ij[3*e+2], __int_as_float(s)};
            __builtin_nontemporal_store(v4, (f32x4*)&rsrt[p]);
        } else {
            order[p] = e;
            srcs[p] = s;
        }
    }
}

// ---------------- fused edge kernel ----------------
// r14 body at 3 blocks/CU (r15 re-confirmed 4/CU thrashes L2 even with NT
// stores: WRITE 136->222MB, edge 156->210us). + s_setprio(1) around MFMA
// clusters (T5): blocks are independent & barrier-light -> scheduler can
// favor MFMA-entering waves (attn-like case, m191), unlike lockstep GEMM.
__global__ __launch_bounds__(256, 3) void edge_kernel(
    const float* __restrict__ r_ij,
    const int* __restrict__ order, const int* __restrict__ srcs,
    const float4* __restrict__ rsrt, int use_rsrt,
    const unsigned short* __restrict__ wp,
    const float* __restrict__ b0, const float* __restrict__ b1, const float* __restrict__ b2,
    float* __restrict__ A_a, float* __restrict__ Ov, int E)
{
    __shared__ unsigned short h_s[16896];
    __shared__ unsigned short rvb_s[3 * 128];      // bf16 rv, [c][row]
    __shared__ unsigned char  segid_s[128];
    __shared__ int  segnode_s[128];
    __shared__ int  src_s[128];
    __shared__ int  nseg_s;

    const int tid = threadIdx.x;
    const int w  = tid >> 6;
    const int l  = tid & 63;
    const int e0 = xcd_swizzle(blockIdx.x, gridDim.x) * 128;
    const int lr = l & 15;
    const int lg = l >> 4;
    const int mbase = w * 32;

    // ---- stage per-edge scalars
    if (l < 32) {
        const int ml = mbase + l;
        const int pos = e0 + ml;
        float x = 0.f, y = 0.f, z = 0.f; int s = -1;
        if (pos < E) {
            if (use_rsrt) {
                f32x4 t4 = __builtin_nontemporal_load((const f32x4*)&rsrt[pos]);
                x = t4[0]; y = t4[1]; z = t4[2]; s = __float_as_int(t4[3]);
            } else {
                int e = order[pos];
                s = srcs[pos];
                x = r_ij[3*e]; y = r_ij[3*e+1]; z = r_ij[3*e+2];
            }
        }
        float r = sqrtf(x*x + y*y + z*z);
        float u = r * 4.0f;               // r * 8/R0, R0=2
        s16x8 ev;
        #pragma unroll
        for (int k = 0; k < 8; k++) {
            float t = fmaxf(1.0f - fabsf(u - (float)k), 0.0f);
            ev[k] = (short)f2bf((s >= 0) ? t : 0.0f);
        }
        *(s16x8*)&h_s[ml * 104 + 96] = ev;     // enc into pad cols
        float nn = 3.5f * r;
        float sc = (s >= 0) ? (3.5f * tanhf(nn) / fmaxf(nn, 1e-12f)) : 0.0f;
        rvb_s[0*128 + ml] = f2bf(x * sc);
        rvb_s[1*128 + ml] = f2bf(y * sc);
        rvb_s[2*128 + ml] = f2bf(z * sc);
        src_s[ml] = s;
    }
    __syncthreads();   // SYNC#1: src_s/enc visible

    // ---- wave 0: build segid / segnode / nseg (ballot-based prefix)
    if (w == 0) {
        int i = l;
        int sA = src_s[i];
        bool fA = (i == 0) || (sA != src_s[i - 1]);
        unsigned long long mA = __ballot(fA);
        unsigned long long maskA = (~0ull) >> (63 - i);
        int incA = (int)__popcll(mA & maskA);
        segid_s[i] = (unsigned char)(incA - 1);
        if (fA) segnode_s[incA - 1] = sA;
        int totA = (int)__popcll(mA);
        int jrow = 64 + i;
        int sB = src_s[jrow];
        bool fB = (sB != src_s[jrow - 1]);
        unsigned long long mB = __ballot(fB);
        int incB = (int)__popcll(mB & maskA);
        segid_s[jrow] = (unsigned char)(totA + incB - 1);
        if (fB) segnode_s[totA + incB - 1] = sB;
        if (i == 63) nseg_s = totA + (int)__popcll(mB);
    }

    // ---- biases as float4 per (nt, lg): feat = nt*16 + lg*4 + jj (swapped D)
    f32x4 b0v4[6], b1v4[6], b2v4[6];
    #pragma unroll
    for (int nt = 0; nt < 6; nt++) {
        float4 t0 = *(const float4*)&b0[nt*16 + lg*4];
        float4 t1 = *(const float4*)&b1[nt*16 + lg*4];
        float4 t2 = *(const float4*)&b2[nt*16 + lg*4];
        b0v4[nt] = (f32x4){t0.x, t0.y, t0.z, t0.w};
        b1v4[nt] = (f32x4){t1.x, t1.y, t1.z, t1.w};
        b2v4[nt] = (f32x4){t2.x, t2.y, t2.z, t2.w};
    }

    __builtin_amdgcn_s_setprio(1);     // favor MFMA-issuing waves (T5)

    // ---- layer 0 (swapped): D[feat][edge] = w0_frag x enc_frag + b0
    {
        s16x8 hb[2];
        #pragma unroll
        for (int mf = 0; mf < 2; mf++) {
            s16x8 a = {0,0,0,0,0,0,0,0};
            if (l < 16) a = *(const s16x8*)&h_s[(mbase + mf*16 + lr) * 104 + 96];
            hb[mf] = a;
        }
        f32x4 acc[2][6];
        #pragma unroll
        for (int nt = 0; nt < 6; nt++) {
            s16x8 Wf = *(const s16x8*)&wp[nt * 512 + l * 8];
            acc[0][nt] = __builtin_amdgcn_mfma_f32_16x16x32_bf16(Wf, hb[0], b0v4[nt], 0, 0, 0);
            acc[1][nt] = __builtin_amdgcn_mfma_f32_16x16x32_bf16(Wf, hb[1], b0v4[nt], 0, 0, 0);
        }
        #pragma unroll
        for (int mf = 0; mf < 2; mf++)
        #pragma unroll
        for (int nt = 0; nt < 6; nt++)
            *(uint2*)&h_s[(mbase + mf*16 + lr) * 104 + nt*16 + lg*4] =
                pack4(acc[mf][nt][0], acc[mf][nt][1], acc[mf][nt][2], acc[mf][nt][3]);
    }

    // ---- layers 1,2 (swapped): in-place leaky(W x h + b); b64 epilogue
    #pragma unroll
    for (int li = 0; li < 2; li++) {
        const int poff = 3072 + li * 9216;
        s16x8 A[2][3];
        #pragma unroll
        for (int mf = 0; mf < 2; mf++)
        #pragma unroll
        for (int kt = 0; kt < 3; kt++)
            A[mf][kt] = *(const s16x8*)&h_s[(mbase + mf*16 + lr) * 104 + kt*32 + lg*8];
        f32x4 a2[2][6];
        #pragma unroll
        for (int nt = 0; nt < 6; nt++) {
            f32x4 bi = (li == 0) ? b1v4[nt] : b2v4[nt];
            a2[0][nt] = bi; a2[1][nt] = bi;
        }
        #pragma unroll
        for (int nt = 0; nt < 6; nt++)
        #pragma unroll
        for (int kt = 0; kt < 3; kt++) {
            s16x8 Wf = *(const s16x8*)&wp[poff + (kt*6 + nt) * 512 + l * 8];
            a2[0][nt] = __builtin_amdgcn_mfma_f32_16x16x32_bf16(Wf, A[0][kt], a2[0][nt], 0, 0, 0);
            a2[1][nt] = __builtin_amdgcn_mfma_f32_16x16x32_bf16(Wf, A[1][kt], a2[1][nt], 0, 0, 0);
        }
        #pragma unroll
        for (int mf = 0; mf < 2; mf++)
        #pragma unroll
        for (int nt = 0; nt < 6; nt++) {
            float q0 = a2[mf][nt][0], q1 = a2[mf][nt][1];
            float q2 = a2[mf][nt][2], q3 = a2[mf][nt][3];
            q0 = fmaxf(q0, 0.1f*q0); q1 = fmaxf(q1, 0.1f*q1);
            q2 = fmaxf(q2, 0.1f*q2); q3 = fmaxf(q3, 0.1f*q3);
            *(uint2*)&h_s[(mbase + mf*16 + lr) * 104 + nt*16 + lg*4] = pack4(q0, q1, q2, q3);
        }
    }

    // ---- layer 3 (old orientation): rad = h @ w3.T -> packed regs
    uint2 radp[2][6];
    {
        s16x8 A[2][3];
        #pragma unroll
        for (int mf = 0; mf < 2; mf++)
        #pragma unroll
        for (int kt = 0; kt < 3; kt++)
            A[mf][kt] = *(const s16x8*)&h_s[(mbase + mf*16 + lr) * 104 + kt*32 + lg*8];
        f32x4 rad[2][6] = {};
        #pragma unroll
        for (int nt = 0; nt < 6; nt++)
        #pragma unroll
        for (int kt = 0; kt < 3; kt++) {
            s16x8 B = *(const s16x8*)&wp[21504 + (kt*6 + nt) * 512 + l * 8];
            rad[0][nt] = __builtin_amdgcn_mfma_f32_16x16x32_bf16(A[0][kt], B, rad[0][nt], 0, 0, 0);
            rad[1][nt] = __builtin_amdgcn_mfma_f32_16x16x32_bf16(A[1][kt], B, rad[1][nt], 0, 0, 0);
        }
        #pragma unroll
        for (int mf = 0; mf < 2; mf++)
        #pragma unroll
        for (int nt = 0; nt < 6; nt++)
            radp[mf][nt] = pack4(rad[mf][nt][0], rad[mf][nt][1], rad[mf][nt][2], rad[mf][nt][3]);
    }

    __builtin_amdgcn_s_setprio(0);

    __syncthreads();   // SYNC#2: all row-major reads of h done -> overlay allowed

    // ---- rad -> B-fragment-order stash (overlays h_s[0 .. 12288 u16))
    #pragma unroll
    for (int mf = 0; mf < 2; mf++)
    #pragma unroll
    for (int nt = 0; nt < 6; nt++)
        *(uint2*)&h_s[(w*6 + nt) * 512 + ((2*mf + (lg>>1))*16 + lr) * 8 + (lg&1)*4] = radp[mf][nt];

    __syncthreads();   // SYNC#3: rad frags + segid visible

    // ---- segment reduction (interior segs: plain NT store; boundary: atomic)
    const int nseg = nseg_s;
    if (w == 0) {
        for (int st = 0; st * 16 < nseg; ++st) {
            const int target = st * 16 + lr;
            f32x4 acc[6] = {};
            __builtin_amdgcn_s_setprio(1);
            #pragma unroll
            for (int kt = 0; kt < 4; kt++) {
                uint2 sid8 = *(const uint2*)&segid_s[kt*32 + 8*lg];
                s16x8 af;
                #pragma unroll
                for (int j = 0; j < 8; j++) {
                    unsigned word = (j < 4) ? sid8.x : sid8.y;
                    int sid = (word >> (8 * (j & 3))) & 255;
                    af[j] = (short)((sid == target) ? 0x3F80 : 0);
                }
                #pragma unroll
                for (int nt = 0; nt < 6; nt++) {
                    s16x8 B = *(const s16x8*)&h_s[(kt*6 + nt) * 512 + l * 8];
                    acc[nt] = __builtin_amdgcn_mfma_f32_16x16x32_bf16(af, B, acc[nt], 0, 0, 0);
                }
            }
            __builtin_amdgcn_s_setprio(0);
            #pragma unroll
            for (int nt = 0; nt < 6; nt++)
            #pragma unroll
            for (int j = 0; j < 4; j++) {
                int g = st*16 + 4*lg + j;
                if (g < nseg) {
                    int node = segnode_s[g];
                    if (node >= 0) {
                        float* p = &A_a[node*96 + nt*16 + lr];
                        if (g == 0 || g == nseg - 1) unsafeAtomicAdd(p, acc[nt][j]);
                        else __builtin_nontemporal_store(acc[nt][j], p);
                    }
                }
            }
        }
    } else {
        const int c = w - 1;
        const int scb = 12288 + (w - 1) * 1536;
        for (int st = 0; st * 16 < nseg; ++st) {
            const int target = st * 16 + lr;
            f32x4 acc6[6] = {};
            __builtin_amdgcn_s_setprio(1);
            #pragma unroll
            for (int kt = 0; kt < 4; kt++) {
                uint2 sid8 = *(const uint2*)&segid_s[kt*32 + 8*lg];
                s16x8 rv8 = *(const s16x8*)&rvb_s[c*128 + kt*32 + 8*lg];
                s16x8 af;
                #pragma unroll
                for (int j = 0; j < 8; j++) {
                    unsigned word = (j < 4) ? sid8.x : sid8.y;
                    int sid = (word >> (8 * (j & 3))) & 255;
                    af[j] = (sid == target) ? rv8[j] : (short)0;
                }
                #pragma unroll
                for (int nt = 0; nt < 6; nt++) {
                    s16x8 B = *(const s16x8*)&h_s[(kt*6 + nt) * 512 + l * 8];
                    acc6[nt] = __builtin_amdgcn_mfma_f32_16x16x32_bf16(af, B, acc6[nt], 0, 0, 0);
                }
            }
            #pragma unroll
            for (int nt = 0; nt < 6; nt++) {
                int ktf = nt >> 1;
                int lane2 = ((nt & 1) * 2 + (lr >> 3)) * 16 + 4*lg;
                int a0 = scb + ktf*512 + lane2*8 + (lr & 7);
                h_s[a0]      = f2bf(acc6[nt][0]);
                h_s[a0 + 8]  = f2bf(acc6[nt][1]);
                h_s[a0 + 16] = f2bf(acc6[nt][2]);
                h_s[a0 + 24] = f2bf(acc6[nt][3]);
            }
            s16x8 As[3];
            #pragma unroll
            for (int ktf = 0; ktf < 3; ktf++)
                As[ktf] = *(const s16x8*)&h_s[scb + ktf*512 + l*8];
            f32x4 acc2[4] = {};
            #pragma unroll
            for (int vt = 0; vt < 4; vt++)
            #pragma unroll
            for (int ktf = 0; ktf < 3; ktf++) {
                s16x8 B = *(const s16x8*)&wp[30720 + (ktf*4 + vt) * 512 + l * 8];
                acc2[vt] = __builtin_amdgcn_mfma_f32_16x16x32_bf16(As[ktf], B, acc2[vt], 0, 0, 0);
            }
            __builtin_amdgcn_s_setprio(0);
            #pragma unroll
            for (int vt = 0; vt < 4; vt++)
            #pragma unroll
            for (int j = 0; j < 4; j++) {
                int g = st*16 + 4*lg + j;
                if (g < nseg) {
                    int node = segnode_s[g];
                    if (node >= 0) {
                        float* p = &Ov[node*192 + (vt*16 + lr)*3 + c];
                        if (g == 0 || g == nseg - 1) unsafeAtomicAdd(p, acc2[vt][j]);
                        else __builtin_nontemporal_store(acc2[vt][j], p);
                    }
                }
            }
        }
    }
}

extern "C" void kernel_launch(void* const* d_in, const int* in_sizes, int n_in,
                              void* d_out, int out_size, void* d_ws, size_t ws_size,
                              hipStream_t stream)
{
    const float* r_ij = (const float*)d_in[0];
    const float* w0   = (const float*)d_in[1];
    const float* b0   = (const float*)d_in[2];
    const float* w1   = (const float*)d_in[3];
    const float* b1   = (const float*)d_in[4];
    const float* w2   = (const float*)d_in[5];
    const float* b2   = (const float*)d_in[6];
    const float* w3   = (const float*)d_in[7];
    const float* wv   = (const float*)d_in[8];
    const int*   src  = (const int*)d_in[9];
    const int E = in_sizes[0] / 3;
    const int N = out_size / 288;
    float* A_a = (float*)d_out;
    float* Ov  = A_a + (size_t)N * 96;

    char* wsb = (char*)d_ws;
    unsigned short* wp = (unsigned short*)wsb;                  // 73728 B
    size_t off = 73728;
    int* counts = (int*)(wsb + off);  off += (((size_t)N*4 + 127) & ~127ull);
    int* cursor = (int*)(wsb + off);  off += (((size_t)N*4 + 127) & ~127ull);
    int* bsum   = (int*)(wsb + off);  off += 1024;
    size_t need_rsrt = off + (size_t)E * 16;
    int use_rsrt = (need_rsrt <= ws_size) ? 1 : 0;
    float4* rsrt = (float4*)(wsb + off);
    int* order   = (int*)(wsb + off);
    int* srcs    = (int*)(wsb + off + (((size_t)E*4 + 127) & ~127ull));

    const int nb = (N + 2047) / 2048;
    const long nz = (long)out_size / 4;     // out_size = 288*N, divisible by 4

    pack_weights_k<<<(PACK_TOT + 255) / 256, 256, 0, stream>>>(w0, w1, w2, w3, wv, wp,
                                                               counts, N);
    hist_k<<<(E + 255) / 256, 256, 0, stream>>>(src, counts, (float4*)d_out, nz, E);
    scan1_k<<<nb, 256, 0, stream>>>(counts, cursor, bsum, N);
    scatter_k<<<(E + 255) / 256, 256, 0, stream>>>(src, r_ij, bsum, cursor,
                                                   order, srcs, rsrt, use_rsrt, nb, E);
    edge_kernel<<<(E + 127) / 128, 256, 0, stream>>>(r_ij, order, srcs, rsrt, use_rsrt,
                                                     wp, b0, b1, b2, A_a, Ov, E);
}

// Round 17
// 228.724 us; speedup vs baseline: 1.1523x; 1.0588x over previous
//
#include <hip/hip_runtime.h>
#include <math.h>

typedef float f32x4 __attribute__((ext_vector_type(4)));
typedef short s16x8 __attribute__((ext_vector_type(8)));

__device__ __forceinline__ unsigned short f2bf(float f) {
    unsigned u = __builtin_bit_cast(unsigned, f);
    u += 0x7fffu + ((u >> 16) & 1u);
    return (unsigned short)(u >> 16);
}

// Pack 4 f32 -> 4 bf16 (round-half-up) via v_perm_b32 (builtin, no asm).
__device__ __forceinline__ uint2 pack4(float q0, float q1, float q2, float q3) {
    unsigned u0 = __builtin_bit_cast(unsigned, q0) + 0x8000u;
    unsigned u1 = __builtin_bit_cast(unsigned, q1) + 0x8000u;
    unsigned u2 = __builtin_bit_cast(unsigned, q2) + 0x8000u;
    unsigned u3 = __builtin_bit_cast(unsigned, q3) + 0x8000u;
    uint2 r;
    r.x = __builtin_amdgcn_perm(u1, u0, 0x07060302);
    r.y = __builtin_amdgcn_perm(u3, u2, 0x07060302);
    return r;
}

// Bijective XCD-chunking swizzle (kept; harmless).
__device__ __forceinline__ int xcd_swizzle(int b, int nwg) {
    int q = nwg >> 3, r = nwg & 7;
    int xcd = b & 7, slot = b >> 3;
    int base = (xcd < r) ? xcd * (q + 1) : r * (q + 1) + (xcd - r) * q;
    return base + slot;
}

// ---------------- weight packing (+ fused counts zeroing) ----------------
// Frag (kt,nt): lane l elem j holds W[16nt+(l&15)][32kt+8*(l>>4)+j].
#define PACK_TOT 36864

__global__ __launch_bounds__(256) void pack_weights_k(
    const float* __restrict__ w0, const float* __restrict__ w1,
    const float* __restrict__ w2, const float* __restrict__ w3,
    const float* __restrict__ wv, unsigned short* __restrict__ dst,
    int* __restrict__ counts, int N)
{
    int idx = blockIdx.x * 256 + threadIdx.x;
    int stride = gridDim.x * 256;
    for (int i = idx; i < N; i += stride) counts[i] = 0;   // replaces memset(counts)
    if (idx >= PACK_TOT) return;
    const float* W; int inF, ntiles, off;
    if (idx < 3072)       { W = w0; inF = 8;  ntiles = 6; off = 0; }
    else if (idx < 12288) { W = w1; inF = 96; ntiles = 6; off = 3072; }
    else if (idx < 21504) { W = w2; inF = 96; ntiles = 6; off = 12288; }
    else if (idx < 30720) { W = w3; inF = 96; ntiles = 6; off = 21504; }
    else                  { W = wv; inF = 96; ntiles = 4; off = 30720; }
    int r  = idx - off;
    int fi = r >> 9;
    int wi = r & 511;
    int l = wi >> 3, j = wi & 7;
    int kt = fi / ntiles, nt = fi - kt * ntiles;
    int n = nt * 16 + (l & 15);
    int k = kt * 32 + ((l >> 4) << 3) + j;
    float v = (k < inF) ? W[n * inF + k] : 0.0f;
    dst[idx] = f2bf(v);
}

// ---------------- CSR build (+ fused d_out zeroing, PLAIN stores: the
// zero lines are read back by the edge kernel's RMWs — keep them in L2.
// (r16 measured NT zeroing: edge FETCH 8.2->9.9MB, dur +13us. Reverted.)
__global__ __launch_bounds__(256) void hist_k(const int* __restrict__ src,
                                              int* __restrict__ counts,
                                              float4* __restrict__ dz, long nz,
                                              int E)
{
    long tid = (long)blockIdx.x * 256 + threadIdx.x;
    long stride = (long)gridDim.x * 256;
    float4 z4 = make_float4(0.f, 0.f, 0.f, 0.f);
    for (long i = tid; i < nz; i += stride) dz[i] = z4;     // replaces memset(d_out)
    int e = blockIdx.x * 256 + threadIdx.x;
    if (e < E) atomicAdd(&counts[src[e]], 1);
}

__global__ __launch_bounds__(256) void scan1_k(const int* __restrict__ counts,
                                               int* __restrict__ cursor,
                                               int* __restrict__ bsum, int N)
{
    __shared__ int wsum_s[4];
    int b = blockIdx.x, t = threadIdx.x, lane = t & 63, wid = t >> 6;
    int i0 = b * 2048 + t * 8;
    int v[8]; int s = 0;
    #pragma unroll
    for (int j = 0; j < 8; j++) { int i = i0 + j; v[j] = (i < N) ? counts[i] : 0; s += v[j]; }
    int inc = s;
    #pragma unroll
    for (int d = 1; d < 64; d <<= 1) { int o = __shfl_up(inc, d, 64); if (lane >= d) inc += o; }
    if (lane == 63) wsum_s[wid] = inc;
    __syncthreads();
    int wb = 0;
    for (int k = 0; k < wid; k++) wb += wsum_s[k];
    int run = wb + inc - s;
    #pragma unroll
    for (int j = 0; j < 8; j++) { int i = i0 + j; if (i < N) cursor[i] = run; run += v[j]; }
    if (t == 255) bsum[b] = wb + inc;
}

// scatter with inline chunk-total prefix; rsrt written non-temporally
__global__ __launch_bounds__(256) void scatter_k(const int* __restrict__ src,
                                                 const float* __restrict__ r_ij,
                                                 const int* __restrict__ bsum,
                                                 int* __restrict__ cursor,
                                                 int* __restrict__ order,
                                                 int* __restrict__ srcs,
                                                 float4* __restrict__ rsrt,
                                                 int use_rsrt, int nb, int E)
{
    __shared__ int pre_s[256];
    int t = threadIdx.x;
    if (t < 64) {
        int carry = 0;
        for (int base = 0; base < nb; base += 64) {
            int i = base + t;
            int v = (i < nb) ? bsum[i] : 0;
            int inc = v;
            #pragma unroll
            for (int d = 1; d < 64; d <<= 1) {
                int o = __shfl_up(inc, d, 64);
                if (t >= d) inc += o;
            }
            if (i < nb) pre_s[i] = carry + inc - v;
            carry += __shfl(inc, 63);
        }
    }
    __syncthreads();
    int e = blockIdx.x * 256 + t;
    if (e < E) {
        int s = src[e];
        int p = pre_s[s >> 11] + atomicAdd(&cursor[s], 1);
        if (use_rsrt) {
            f32x4 v4 = {r_ij[3*e], r_ij[3*e+1], r_ij[3*e+2], __int_as_float(s)};
            __builtin_nontemporal_store(v4, (f32x4*)&rsrt[p]);
        } else {
            order[p] = e;
            srcs[p] = s;
        }
    }
}

// ---------------- fused edge kernel (r14 configuration — measured optimum) ----
// 3 blocks/CU (4/CU thrashes per-XCD L2: r9/r10/r15); no setprio (r16: hurts
// barrier-synced waves); interior-segment NT stores (r14: -10us, WRITE -14MB).
__global__ __launch_bounds__(256, 3) void edge_kernel(
    const float* __restrict__ r_ij,
    const int* __restrict__ order, const int* __restrict__ srcs,
    const float4* __restrict__ rsrt, int use_rsrt,
    const unsigned short* __restrict__ wp,
    const float* __restrict__ b0, const float* __restrict__ b1, const float* __restrict__ b2,
    float* __restrict__ A_a, float* __restrict__ Ov, int E)
{
    __shared__ unsigned short h_s[16896];
    __shared__ unsigned short rvb_s[3 * 128];      // bf16 rv, [c][row]
    __shared__ unsigned char  segid_s[128];
    __shared__ int  segnode_s[128];
    __shared__ int  src_s[128];
    __shared__ int  nseg_s;

    const int tid = threadIdx.x;
    const int w  = tid >> 6;
    const int l  = tid & 63;
    const int e0 = xcd_swizzle(blockIdx.x, gridDim.x) * 128;
    const int lr = l & 15;
    const int lg = l >> 4;
    const int mbase = w * 32;

    // ---- stage per-edge scalars
    if (l < 32) {
        const int ml = mbase + l;
        const int pos = e0 + ml;
        float x = 0.f, y = 0.f, z = 0.f; int s = -1;
        if (pos < E) {
            if (use_rsrt) {
                f32x4 t4 = __builtin_nontemporal_load((const f32x4*)&rsrt[pos]);
                x = t4[0]; y = t4[1]; z = t4[2]; s = __float_as_int(t4[3]);
            } else {
                int e = order[pos];
                s = srcs[pos];
                x = r_ij[3*e]; y = r_ij[3*e+1]; z = r_ij[3*e+2];
            }
        }
        float r = sqrtf(x*x + y*y + z*z);
        float u = r * 4.0f;               // r * 8/R0, R0=2
        s16x8 ev;
        #pragma unroll
        for (int k = 0; k < 8; k++) {
            float t = fmaxf(1.0f - fabsf(u - (float)k), 0.0f);
            ev[k] = (short)f2bf((s >= 0) ? t : 0.0f);
        }
        *(s16x8*)&h_s[ml * 104 + 96] = ev;     // enc into pad cols
        float nn = 3.5f * r;
        float sc = (s >= 0) ? (3.5f * tanhf(nn) / fmaxf(nn, 1e-12f)) : 0.0f;
        rvb_s[0*128 + ml] = f2bf(x * sc);
        rvb_s[1*128 + ml] = f2bf(y * sc);
        rvb_s[2*128 + ml] = f2bf(z * sc);
        src_s[ml] = s;
    }
    __syncthreads();   // SYNC#1: src_s/enc visible

    // ---- wave 0: build segid / segnode / nseg (ballot-based prefix)
    if (w == 0) {
        int i = l;
        int sA = src_s[i];
        bool fA = (i == 0) || (sA != src_s[i - 1]);
        unsigned long long mA = __ballot(fA);
        unsigned long long maskA = (~0ull) >> (63 - i);
        int incA = (int)__popcll(mA & maskA);
        segid_s[i] = (unsigned char)(incA - 1);
        if (fA) segnode_s[incA - 1] = sA;
        int totA = (int)__popcll(mA);
        int jrow = 64 + i;
        int sB = src_s[jrow];
        bool fB = (sB != src_s[jrow - 1]);
        unsigned long long mB = __ballot(fB);
        int incB = (int)__popcll(mB & maskA);
        segid_s[jrow] = (unsigned char)(totA + incB - 1);
        if (fB) segnode_s[totA + incB - 1] = sB;
        if (i == 63) nseg_s = totA + (int)__popcll(mB);
    }

    // ---- biases as float4 per (nt, lg): feat = nt*16 + lg*4 + jj (swapped D)
    f32x4 b0v4[6], b1v4[6], b2v4[6];
    #pragma unroll
    for (int nt = 0; nt < 6; nt++) {
        float4 t0 = *(const float4*)&b0[nt*16 + lg*4];
        float4 t1 = *(const float4*)&b1[nt*16 + lg*4];
        float4 t2 = *(const float4*)&b2[nt*16 + lg*4];
        b0v4[nt] = (f32x4){t0.x, t0.y, t0.z, t0.w};
        b1v4[nt] = (f32x4){t1.x, t1.y, t1.z, t1.w};
        b2v4[nt] = (f32x4){t2.x, t2.y, t2.z, t2.w};
    }

    // ---- layer 0 (swapped): D[feat][edge] = w0_frag x enc_frag + b0
    {
        s16x8 hb[2];
        #pragma unroll
        for (int mf = 0; mf < 2; mf++) {
            s16x8 a = {0,0,0,0,0,0,0,0};
            if (l < 16) a = *(const s16x8*)&h_s[(mbase + mf*16 + lr) * 104 + 96];
            hb[mf] = a;
        }
        f32x4 acc[2][6];
        #pragma unroll
        for (int nt = 0; nt < 6; nt++) {
            s16x8 Wf = *(const s16x8*)&wp[nt * 512 + l * 8];
            acc[0][nt] = __builtin_amdgcn_mfma_f32_16x16x32_bf16(Wf, hb[0], b0v4[nt], 0, 0, 0);
            acc[1][nt] = __builtin_amdgcn_mfma_f32_16x16x32_bf16(Wf, hb[1], b0v4[nt], 0, 0, 0);
        }
        #pragma unroll
        for (int mf = 0; mf < 2; mf++)
        #pragma unroll
        for (int nt = 0; nt < 6; nt++)
            *(uint2*)&h_s[(mbase + mf*16 + lr) * 104 + nt*16 + lg*4] =
                pack4(acc[mf][nt][0], acc[mf][nt][1], acc[mf][nt][2], acc[mf][nt][3]);
    }

    // ---- layers 1,2 (swapped): in-place leaky(W x h + b); b64 epilogue
    #pragma unroll
    for (int li = 0; li < 2; li++) {
        const int poff = 3072 + li * 9216;
        s16x8 A[2][3];
        #pragma unroll
        for (int mf = 0; mf < 2; mf++)
        #pragma unroll
        for (int kt = 0; kt < 3; kt++)
            A[mf][kt] = *(const s16x8*)&h_s[(mbase + mf*16 + lr) * 104 + kt*32 + lg*8];
        f32x4 a2[2][6];
        #pragma unroll
        for (int nt = 0; nt < 6; nt++) {
            f32x4 bi = (li == 0) ? b1v4[nt] : b2v4[nt];
            a2[0][nt] = bi; a2[1][nt] = bi;
        }
        #pragma unroll
        for (int nt = 0; nt < 6; nt++)
        #pragma unroll
        for (int kt = 0; kt < 3; kt++) {
            s16x8 Wf = *(const s16x8*)&wp[poff + (kt*6 + nt) * 512 + l * 8];
            a2[0][nt] = __builtin_amdgcn_mfma_f32_16x16x32_bf16(Wf, A[0][kt], a2[0][nt], 0, 0, 0);
            a2[1][nt] = __builtin_amdgcn_mfma_f32_16x16x32_bf16(Wf, A[1][kt], a2[1][nt], 0, 0, 0);
        }
        #pragma unroll
        for (int mf = 0; mf < 2; mf++)
        #pragma unroll
        for (int nt = 0; nt < 6; nt++) {
            float q0 = a2[mf][nt][0], q1 = a2[mf][nt][1];
            float q2 = a2[mf][nt][2], q3 = a2[mf][nt][3];
            q0 = fmaxf(q0, 0.1f*q0); q1 = fmaxf(q1, 0.1f*q1);
            q2 = fmaxf(q2, 0.1f*q2); q3 = fmaxf(q3, 0.1f*q3);
            *(uint2*)&h_s[(mbase + mf*16 + lr) * 104 + nt*16 + lg*4] = pack4(q0, q1, q2, q3);
        }
    }

    // ---- layer 3 (old orientation): rad = h @ w3.T -> packed regs
    uint2 radp[2][6];
    {
        s16x8 A[2][3];
        #pragma unroll
        for (int mf = 0; mf < 2; mf++)
        #pragma unroll
        for (int kt = 0; kt < 3; kt++)
            A[mf][kt] = *(const s16x8*)&h_s[(mbase + mf*16 + lr) * 104 + kt*32 + lg*8];
        f32x4 rad[2][6] = {};
        #pragma unroll
        for (int nt = 0; nt < 6; nt++)
        #pragma unroll
        for (int kt = 0; kt < 3; kt++) {
            s16x8 B = *(const s16x8*)&wp[21504 + (kt*6 + nt) * 512 + l * 8];
            rad[0][nt] = __builtin_amdgcn_mfma_f32_16x16x32_bf16(A[0][kt], B, rad[0][nt], 0, 0, 0);
            rad[1][nt] = __builtin_amdgcn_mfma_f32_16x16x32_bf16(A[1][kt], B, rad[1][nt], 0, 0, 0);
        }
        #pragma unroll
        for (int mf = 0; mf < 2; mf++)
        #pragma unroll
        for (int nt = 0; nt < 6; nt++)
            radp[mf][nt] = pack4(rad[mf][nt][0], rad[mf][nt][1], rad[mf][nt][2], rad[mf][nt][3]);
    }

    __syncthreads();   // SYNC#2: all row-major reads of h done -> overlay allowed

    // ---- rad -> B-fragment-order stash (overlays h_s[0 .. 12288 u16))
    #pragma unroll
    for (int mf = 0; mf < 2; mf++)
    #pragma unroll
    for (int nt = 0; nt < 6; nt++)
        *(uint2*)&h_s[(w*6 + nt) * 512 + ((2*mf + (lg>>1))*16 + lr) * 8 + (lg&1)*4] = radp[mf][nt];

    __syncthreads();   // SYNC#3: rad frags + segid visible

    // ---- segment reduction (interior segs: plain NT store; boundary: atomic)
    const int nseg = nseg_s;
    if (w == 0) {
        for (int st = 0; st * 16 < nseg; ++st) {
            const int target = st * 16 + lr;
            f32x4 acc[6] = {};
            #pragma unroll
            for (int kt = 0; kt < 4; kt++) {
                uint2 sid8 = *(const uint2*)&segid_s[kt*32 + 8*lg];
                s16x8 af;
                #pragma unroll
                for (int j = 0; j < 8; j++) {
                    unsigned word = (j < 4) ? sid8.x : sid8.y;
                    int sid = (word >> (8 * (j & 3))) & 255;
                    af[j] = (short)((sid == target) ? 0x3F80 : 0);
                }
                #pragma unroll
                for (int nt = 0; nt < 6; nt++) {
                    s16x8 B = *(const s16x8*)&h_s[(kt*6 + nt) * 512 + l * 8];
                    acc[nt] = __builtin_amdgcn_mfma_f32_16x16x32_bf16(af, B, acc[nt], 0, 0, 0);
                }
            }
            #pragma unroll
            for (int nt = 0; nt < 6; nt++)
            #pragma unroll
            for (int j = 0; j < 4; j++) {
                int g = st*16 + 4*lg + j;
                if (g < nseg) {
                    int node = segnode_s[g];
                    if (node >= 0) {
                        float* p = &A_a[node*96 + nt*16 + lr];
                        if (g == 0 || g == nseg - 1) unsafeAtomicAdd(p, acc[nt][j]);
                        else __builtin_nontemporal_store(acc[nt][j], p);
                    }
                }
            }
        }
    } else {
        const int c = w - 1;
        const int scb = 12288 + (w - 1) * 1536;
        for (int st = 0; st * 16 < nseg; ++st) {
            const int target = st * 16 + lr;
            f32x4 acc6[6] = {};
            #pragma unroll
            for (int kt = 0; kt < 4; kt++) {
                uint2 sid8 = *(const uint2*)&segid_s[kt*32 + 8*lg];
                s16x8 rv8 = *(const s16x8*)&rvb_s[c*128 + kt*32 + 8*lg];
                s16x8 af;
                #pragma unroll
                for (int j = 0; j < 8; j++) {
                    unsigned word = (j < 4) ? sid8.x : sid8.y;
                    int sid = (word >> (8 * (j & 3))) & 255;
                    af[j] = (sid == target) ? rv8[j] : (short)0;
                }
                #pragma unroll
                for (int nt = 0; nt < 6; nt++) {
                    s16x8 B = *(const s16x8*)&h_s[(kt*6 + nt) * 512 + l * 8];
                    acc6[nt] = __builtin_amdgcn_mfma_f32_16x16x32_bf16(af, B, acc6[nt], 0, 0, 0);
                }
            }
            #pragma unroll
            for (int nt = 0; nt < 6; nt++) {
                int ktf = nt >> 1;
                int lane2 = ((nt & 1) * 2 + (lr >> 3)) * 16 + 4*lg;
                int a0 = scb + ktf*512 + lane2*8 + (lr & 7);
                h_s[a0]      = f2bf(acc6[nt][0]);
                h_s[a0 + 8]  = f2bf(acc6[nt][1]);
                h_s[a0 + 16] = f2bf(acc6[nt][2]);
                h_s[a0 + 24] = f2bf(acc6[nt][3]);
            }
            s16x8 As[3];
            #pragma unroll
            for (int ktf = 0; ktf < 3; ktf++)
                As[ktf] = *(const s16x8*)&h_s[scb + ktf*512 + l*8];
            f32x4 acc2[4] = {};
            #pragma unroll
            for (int vt = 0; vt < 4; vt++)
            #pragma unroll
            for (int ktf = 0; ktf < 3; ktf++) {
                s16x8 B = *(const s16x8*)&wp[30720 + (ktf*4 + vt) * 512 + l * 8];
                acc2[vt] = __builtin_amdgcn_mfma_f32_16x16x32_bf16(As[ktf], B, acc2[vt], 0, 0, 0);
            }
            #pragma unroll
            for (int vt = 0; vt < 4; vt++)
            #pragma unroll
            for (int j = 0; j < 4; j++) {
                int g = st*16 + 4*lg + j;
                if (g < nseg) {
                    int node = segnode_s[g];
                    if (node >= 0) {
                        float* p = &Ov[node*192 + (vt*16 + lr)*3 + c];
                        if (g == 0 || g == nseg - 1) unsafeAtomicAdd(p, acc2[vt][j]);
                        else __builtin_nontemporal_store(acc2[vt][j], p);
                    }
                }
            }
        }
    }
}

extern "C" void kernel_launch(void* const* d_in, const int* in_sizes, int n_in,
                              void* d_out, int out_size, void* d_ws, size_t ws_size,
                              hipStream_t stream)
{
    const float* r_ij = (const float*)d_in[0];
    const float* w0   = (const float*)d_in[1];
    const float* b0   = (const float*)d_in[2];
    const float* w1   = (const float*)d_in[3];
    const float* b1   = (const float*)d_in[4];
    const float* w2   = (const float*)d_in[5];
    const float* b2   = (const float*)d_in[6];
    const float* w3   = (const float*)d_in[7];
    const float* wv   = (const float*)d_in[8];
    const int*   src  = (const int*)d_in[9];
    const int E = in_sizes[0] / 3;
    const int N = out_size / 288;
    float* A_a = (float*)d_out;
    float* Ov  = A_a + (size_t)N * 96;

    char* wsb = (char*)d_ws;
    unsigned short* wp = (unsigned short*)wsb;                  // 73728 B
    size_t off = 73728;
    int* counts = (int*)(wsb + off);  off += (((size_t)N*4 + 127) & ~127ull);
    int* cursor = (int*)(wsb + off);  off += (((size_t)N*4 + 127) & ~127ull);
    int* bsum   = (int*)(wsb + off);  off += 1024;
    size_t need_rsrt = off + (size_t)E * 16;
    int use_rsrt = (need_rsrt <= ws_size) ? 1 : 0;
    float4* rsrt = (float4*)(wsb + off);
    int* order   = (int*)(wsb + off);
    int* srcs    = (int*)(wsb + off + (((size_t)E*4 + 127) & ~127ull));

    const int nb = (N + 2047) / 2048;
    const long nz = (long)out_size / 4;     // out_size = 288*N, divisible by 4

    pack_weights_k<<<(PACK_TOT + 255) / 256, 256, 0, stream>>>(w0, w1, w2, w3, wv, wp,
                                                               counts, N);
    hist_k<<<(E + 255) / 256, 256, 0, stream>>>(src, counts, (float4*)d_out, nz, E);
    scan1_k<<<nb, 256, 0, stream>>>(counts, cursor, bsum, N);
    scatter_k<<<(E + 255) / 256, 256, 0, stream>>>(src, r_ij, bsum, cursor,
                                                   order, srcs, rsrt, use_rsrt, nb, E);
    edge_kernel<<<(E + 127) / 128, 256, 0, stream>>>(r_ij, order, srcs, rsrt, use_rsrt,
                                                     wp, b0, b1, b2, A_a, Ov, E);
}

// Round 18
// 223.392 us; speedup vs baseline: 1.1798x; 1.0239x over previous
//
#include <hip/hip_runtime.h>
#include <math.h>

typedef float f32x4 __attribute__((ext_vector_type(4)));
typedef short s16x8 __attribute__((ext_vector_type(8)));

__device__ __forceinline__ unsigned short f2bf(float f) {
    unsigned u = __builtin_bit_cast(unsigned, f);
    u += 0x7fffu + ((u >> 16) & 1u);
    return (unsigned short)(u >> 16);
}

// Pack 4 f32 -> 4 bf16 (round-half-up) via v_perm_b32 (builtin, no asm).
__device__ __forceinline__ uint2 pack4(float q0, float q1, float q2, float q3) {
    unsigned u0 = __builtin_bit_cast(unsigned, q0) + 0x8000u;
    unsigned u1 = __builtin_bit_cast(unsigned, q1) + 0x8000u;
    unsigned u2 = __builtin_bit_cast(unsigned, q2) + 0x8000u;
    unsigned u3 = __builtin_bit_cast(unsigned, q3) + 0x8000u;
    uint2 r;
    r.x = __builtin_amdgcn_perm(u1, u0, 0x07060302);
    r.y = __builtin_amdgcn_perm(u3, u2, 0x07060302);
    return r;
}

// Bijective XCD-chunking swizzle (kept; harmless).
__device__ __forceinline__ int xcd_swizzle(int b, int nwg) {
    int q = nwg >> 3, r = nwg & 7;
    int xcd = b & 7, slot = b >> 3;
    int base = (xcd < r) ? xcd * (q + 1) : r * (q + 1) + (xcd - r) * q;
    return base + slot;
}

// ---------------- weight packing (+ fused counts zeroing) ----------------
// Frag (kt,nt): lane l elem j holds W[16nt+(l&15)][32kt+8*(l>>4)+j].
#define PACK_TOT 36864

__global__ __launch_bounds__(256) void pack_weights_k(
    const float* __restrict__ w0, const float* __restrict__ w1,
    const float* __restrict__ w2, const float* __restrict__ w3,
    const float* __restrict__ wv, unsigned short* __restrict__ dst,
    int* __restrict__ counts, int N)
{
    int idx = blockIdx.x * 256 + threadIdx.x;
    int stride = gridDim.x * 256;
    for (int i = idx; i < N; i += stride) counts[i] = 0;   // replaces memset(counts)
    if (idx >= PACK_TOT) return;
    const float* W; int inF, ntiles, off;
    if (idx < 3072)       { W = w0; inF = 8;  ntiles = 6; off = 0; }
    else if (idx < 12288) { W = w1; inF = 96; ntiles = 6; off = 3072; }
    else if (idx < 21504) { W = w2; inF = 96; ntiles = 6; off = 12288; }
    else if (idx < 30720) { W = w3; inF = 96; ntiles = 6; off = 21504; }
    else                  { W = wv; inF = 96; ntiles = 4; off = 30720; }
    int r  = idx - off;
    int fi = r >> 9;
    int wi = r & 511;
    int l = wi >> 3, j = wi & 7;
    int kt = fi / ntiles, nt = fi - kt * ntiles;
    int n = nt * 16 + (l & 15);
    int k = kt * 32 + ((l >> 4) << 3) + j;
    float v = (k < inF) ? W[n * inF + k] : 0.0f;
    dst[idx] = f2bf(v);
}

// ---------------- CSR build (+ fused d_out zeroing, PLAIN stores) ----------
__global__ __launch_bounds__(256) void hist_k(const int* __restrict__ src,
                                              int* __restrict__ counts,
                                              float4* __restrict__ dz, long nz,
                                              int E)
{
    long tid = (long)blockIdx.x * 256 + threadIdx.x;
    long stride = (long)gridDim.x * 256;
    float4 z4 = make_float4(0.f, 0.f, 0.f, 0.f);
    for (long i = tid; i < nz; i += stride) dz[i] = z4;     // replaces memset(d_out)
    int e = blockIdx.x * 256 + threadIdx.x;
    if (e < E) atomicAdd(&counts[src[e]], 1);
}

__global__ __launch_bounds__(256) void scan1_k(const int* __restrict__ counts,
                                               int* __restrict__ cursor,
                                               int* __restrict__ bsum, int N)
{
    __shared__ int wsum_s[4];
    int b = blockIdx.x, t = threadIdx.x, lane = t & 63, wid = t >> 6;
    int i0 = b * 2048 + t * 8;
    int v[8]; int s = 0;
    #pragma unroll
    for (int j = 0; j < 8; j++) { int i = i0 + j; v[j] = (i < N) ? counts[i] : 0; s += v[j]; }
    int inc = s;
    #pragma unroll
    for (int d = 1; d < 64; d <<= 1) { int o = __shfl_up(inc, d, 64); if (lane >= d) inc += o; }
    if (lane == 63) wsum_s[wid] = inc;
    __syncthreads();
    int wb = 0;
    for (int k = 0; k < wid; k++) wb += wsum_s[k];
    int run = wb + inc - s;
    #pragma unroll
    for (int j = 0; j < 8; j++) { int i = i0 + j; if (i < N) cursor[i] = run; run += v[j]; }
    if (t == 255) bsum[b] = wb + inc;
}

// scatter with inline chunk-total prefix; rsrt written non-temporally
__global__ __launch_bounds__(256) void scatter_k(const int* __restrict__ src,
                                                 const float* __restrict__ r_ij,
                                                 const int* __restrict__ bsum,
                                                 int* __restrict__ cursor,
                                                 int* __restrict__ order,
                                                 int* __restrict__ srcs,
                                                 float4* __restrict__ rsrt,
                                                 int use_rsrt, int nb, int E)
{
    __shared__ int pre_s[256];
    int t = threadIdx.x;
    if (t < 64) {
        int carry = 0;
        for (int base = 0; base < nb; base += 64) {
            int i = base + t;
            int v = (i < nb) ? bsum[i] : 0;
            int inc = v;
            #pragma unroll
            for (int d = 1; d < 64; d <<= 1) {
                int o = __shfl_up(inc, d, 64);
                if (t >= d) inc += o;
            }
            if (i < nb) pre_s[i] = carry + inc - v;
            carry += __shfl(inc, 63);
        }
    }
    __syncthreads();
    int e = blockIdx.x * 256 + t;
    if (e < E) {
        int s = src[e];
        int p = pre_s[s >> 11] + atomicAdd(&cursor[s], 1);
        if (use_rsrt) {
            f32x4 v4 = {r_ij[3*e], r_ij[3*e+1], r_ij[3*e+2], __int_as_float(s)};
            __builtin_nontemporal_store(v4, (f32x4*)&rsrt[p]);
        } else {
            order[p] = e;
            srcs[p] = s;
        }
    }
}

// ---------------- fused edge kernel ----------------
// r14 body + Ov write coalescing: waves 1..3 stash acc2 into ov_stage (LDS,
// [seg][v][c] = final layout), then ALL 256 threads flush full 768B/node
// lines contiguously. Kills the 3x stride-12B sector amplification
// (WRITE model: Ov 38.4*3 + A_a 19.2 = 134MB == measured 136MB).
__global__ __launch_bounds__(256, 3) void edge_kernel(
    const float* __restrict__ r_ij,
    const int* __restrict__ order, const int* __restrict__ srcs,
    const float4* __restrict__ rsrt, int use_rsrt,
    const unsigned short* __restrict__ wp,
    const float* __restrict__ b0, const float* __restrict__ b1, const float* __restrict__ b2,
    float* __restrict__ A_a, float* __restrict__ Ov, int E)
{
    __shared__ unsigned short h_s[16896];
    __shared__ __align__(16) float ov_stage[16 * 192];   // 12288 B
    __shared__ unsigned short rvb_s[3 * 128];            // bf16 rv, [c][row]
    __shared__ unsigned char  segid_s[128];
    __shared__ int  segnode_s[128];
    __shared__ int  src_s[128];
    __shared__ int  nseg_s;

    const int tid = threadIdx.x;
    const int w  = tid >> 6;
    const int l  = tid & 63;
    const int e0 = xcd_swizzle(blockIdx.x, gridDim.x) * 128;
    const int lr = l & 15;
    const int lg = l >> 4;
    const int mbase = w * 32;

    // ---- stage per-edge scalars
    if (l < 32) {
        const int ml = mbase + l;
        const int pos = e0 + ml;
        float x = 0.f, y = 0.f, z = 0.f; int s = -1;
        if (pos < E) {
            if (use_rsrt) {
                f32x4 t4 = __builtin_nontemporal_load((const f32x4*)&rsrt[pos]);
                x = t4[0]; y = t4[1]; z = t4[2]; s = __float_as_int(t4[3]);
            } else {
                int e = order[pos];
                s = srcs[pos];
                x = r_ij[3*e]; y = r_ij[3*e+1]; z = r_ij[3*e+2];
            }
        }
        float r = sqrtf(x*x + y*y + z*z);
        float u = r * 4.0f;               // r * 8/R0, R0=2
        s16x8 ev;
        #pragma unroll
        for (int k = 0; k < 8; k++) {
            float t = fmaxf(1.0f - fabsf(u - (float)k), 0.0f);
            ev[k] = (short)f2bf((s >= 0) ? t : 0.0f);
        }
        *(s16x8*)&h_s[ml * 104 + 96] = ev;     // enc into pad cols
        float nn = 3.5f * r;
        float sc = (s >= 0) ? (3.5f * tanhf(nn) / fmaxf(nn, 1e-12f)) : 0.0f;
        rvb_s[0*128 + ml] = f2bf(x * sc);
        rvb_s[1*128 + ml] = f2bf(y * sc);
        rvb_s[2*128 + ml] = f2bf(z * sc);
        src_s[ml] = s;
    }
    __syncthreads();   // SYNC#1: src_s/enc visible

    // ---- wave 0: build segid / segnode / nseg (ballot-based prefix)
    if (w == 0) {
        int i = l;
        int sA = src_s[i];
        bool fA = (i == 0) || (sA != src_s[i - 1]);
        unsigned long long mA = __ballot(fA);
        unsigned long long maskA = (~0ull) >> (63 - i);
        int incA = (int)__popcll(mA & maskA);
        segid_s[i] = (unsigned char)(incA - 1);
        if (fA) segnode_s[incA - 1] = sA;
        int totA = (int)__popcll(mA);
        int jrow = 64 + i;
        int sB = src_s[jrow];
        bool fB = (sB != src_s[jrow - 1]);
        unsigned long long mB = __ballot(fB);
        int incB = (int)__popcll(mB & maskA);
        segid_s[jrow] = (unsigned char)(totA + incB - 1);
        if (fB) segnode_s[totA + incB - 1] = sB;
        if (i == 63) nseg_s = totA + (int)__popcll(mB);
    }

    // ---- biases as float4 per (nt, lg): feat = nt*16 + lg*4 + jj (swapped D)
    f32x4 b0v4[6], b1v4[6], b2v4[6];
    #pragma unroll
    for (int nt = 0; nt < 6; nt++) {
        float4 t0 = *(const float4*)&b0[nt*16 + lg*4];
        float4 t1 = *(const float4*)&b1[nt*16 + lg*4];
        float4 t2 = *(const float4*)&b2[nt*16 + lg*4];
        b0v4[nt] = (f32x4){t0.x, t0.y, t0.z, t0.w};
        b1v4[nt] = (f32x4){t1.x, t1.y, t1.z, t1.w};
        b2v4[nt] = (f32x4){t2.x, t2.y, t2.z, t2.w};
    }

    // ---- layer 0 (swapped): D[feat][edge] = w0_frag x enc_frag + b0
    {
        s16x8 hb[2];
        #pragma unroll
        for (int mf = 0; mf < 2; mf++) {
            s16x8 a = {0,0,0,0,0,0,0,0};
            if (l < 16) a = *(const s16x8*)&h_s[(mbase + mf*16 + lr) * 104 + 96];
            hb[mf] = a;
        }
        f32x4 acc[2][6];
        #pragma unroll
        for (int nt = 0; nt < 6; nt++) {
            s16x8 Wf = *(const s16x8*)&wp[nt * 512 + l * 8];
            acc[0][nt] = __builtin_amdgcn_mfma_f32_16x16x32_bf16(Wf, hb[0], b0v4[nt], 0, 0, 0);
            acc[1][nt] = __builtin_amdgcn_mfma_f32_16x16x32_bf16(Wf, hb[1], b0v4[nt], 0, 0, 0);
        }
        #pragma unroll
        for (int mf = 0; mf < 2; mf++)
        #pragma unroll
        for (int nt = 0; nt < 6; nt++)
            *(uint2*)&h_s[(mbase + mf*16 + lr) * 104 + nt*16 + lg*4] =
                pack4(acc[mf][nt][0], acc[mf][nt][1], acc[mf][nt][2], acc[mf][nt][3]);
    }

    // ---- layers 1,2 (swapped): in-place leaky(W x h + b); b64 epilogue
    #pragma unroll
    for (int li = 0; li < 2; li++) {
        const int poff = 3072 + li * 9216;
        s16x8 A[2][3];
        #pragma unroll
        for (int mf = 0; mf < 2; mf++)
        #pragma unroll
        for (int kt = 0; kt < 3; kt++)
            A[mf][kt] = *(const s16x8*)&h_s[(mbase + mf*16 + lr) * 104 + kt*32 + lg*8];
        f32x4 a2[2][6];
        #pragma unroll
        for (int nt = 0; nt < 6; nt++) {
            f32x4 bi = (li == 0) ? b1v4[nt] : b2v4[nt];
            a2[0][nt] = bi; a2[1][nt] = bi;
        }
        #pragma unroll
        for (int nt = 0; nt < 6; nt++)
        #pragma unroll
        for (int kt = 0; kt < 3; kt++) {
            s16x8 Wf = *(const s16x8*)&wp[poff + (kt*6 + nt) * 512 + l * 8];
            a2[0][nt] = __builtin_amdgcn_mfma_f32_16x16x32_bf16(Wf, A[0][kt], a2[0][nt], 0, 0, 0);
            a2[1][nt] = __builtin_amdgcn_mfma_f32_16x16x32_bf16(Wf, A[1][kt], a2[1][nt], 0, 0, 0);
        }
        #pragma unroll
        for (int mf = 0; mf < 2; mf++)
        #pragma unroll
        for (int nt = 0; nt < 6; nt++) {
            float q0 = a2[mf][nt][0], q1 = a2[mf][nt][1];
            float q2 = a2[mf][nt][2], q3 = a2[mf][nt][3];
            q0 = fmaxf(q0, 0.1f*q0); q1 = fmaxf(q1, 0.1f*q1);
            q2 = fmaxf(q2, 0.1f*q2); q3 = fmaxf(q3, 0.1f*q3);
            *(uint2*)&h_s[(mbase + mf*16 + lr) * 104 + nt*16 + lg*4] = pack4(q0, q1, q2, q3);
        }
    }

    // ---- layer 3 (old orientation): rad = h @ w3.T -> packed regs
    uint2 radp[2][6];
    {
        s16x8 A[2][3];
        #pragma unroll
        for (int mf = 0; mf < 2; mf++)
        #pragma unroll
        for (int kt = 0; kt < 3; kt++)
            A[mf][kt] = *(const s16x8*)&h_s[(mbase + mf*16 + lr) * 104 + kt*32 + lg*8];
        f32x4 rad[2][6] = {};
        #pragma unroll
        for (int nt = 0; nt < 6; nt++)
        #pragma unroll
        for (int kt = 0; kt < 3; kt++) {
            s16x8 B = *(const s16x8*)&wp[21504 + (kt*6 + nt) * 512 + l * 8];
            rad[0][nt] = __builtin_amdgcn_mfma_f32_16x16x32_bf16(A[0][kt], B, rad[0][nt], 0, 0, 0);
            rad[1][nt] = __builtin_amdgcn_mfma_f32_16x16x32_bf16(A[1][kt], B, rad[1][nt], 0, 0, 0);
        }
        #pragma unroll
        for (int mf = 0; mf < 2; mf++)
        #pragma unroll
        for (int nt = 0; nt < 6; nt++)
            radp[mf][nt] = pack4(rad[mf][nt][0], rad[mf][nt][1], rad[mf][nt][2], rad[mf][nt][3]);
    }

    __syncthreads();   // SYNC#2: all row-major reads of h done -> overlay allowed

    // ---- rad -> B-fragment-order stash (overlays h_s[0 .. 12288 u16))
    #pragma unroll
    for (int mf = 0; mf < 2; mf++)
    #pragma unroll
    for (int nt = 0; nt < 6; nt++)
        *(uint2*)&h_s[(w*6 + nt) * 512 + ((2*mf + (lg>>1))*16 + lr) * 8 + (lg&1)*4] = radp[mf][nt];

    __syncthreads();   // SYNC#3: rad frags + segid visible

    // ---- segment reduction; Ov staged in LDS then flushed contiguously
    const int nseg = nseg_s;
    for (int st = 0; st * 16 < nseg; ++st) {
        const int target = st * 16 + lr;
        if (w == 0) {
            // A_a[seg][feat] = I @ rad (64B-contiguous stores, as before)
            f32x4 acc[6] = {};
            #pragma unroll
            for (int kt = 0; kt < 4; kt++) {
                uint2 sid8 = *(const uint2*)&segid_s[kt*32 + 8*lg];
                s16x8 af;
                #pragma unroll
                for (int j = 0; j < 8; j++) {
                    unsigned word = (j < 4) ? sid8.x : sid8.y;
                    int sid = (word >> (8 * (j & 3))) & 255;
                    af[j] = (short)((sid == target) ? 0x3F80 : 0);
                }
                #pragma unroll
                for (int nt = 0; nt < 6; nt++) {
                    s16x8 B = *(const s16x8*)&h_s[(kt*6 + nt) * 512 + l * 8];
                    acc[nt] = __builtin_amdgcn_mfma_f32_16x16x32_bf16(af, B, acc[nt], 0, 0, 0);
                }
            }
            #pragma unroll
            for (int nt = 0; nt < 6; nt++)
            #pragma unroll
            for (int j = 0; j < 4; j++) {
                int g = st*16 + 4*lg + j;
                if (g < nseg) {
                    int node = segnode_s[g];
                    if (node >= 0) {
                        float* p = &A_a[node*96 + nt*16 + lr];
                        if (g == 0 || g == nseg - 1) unsafeAtomicAdd(p, acc[nt][j]);
                        else __builtin_nontemporal_store(acc[nt][j], p);
                    }
                }
            }
        } else {
            // S_c = (I.rv_c) @ rad; stash as A-frags; acc2 = S_c @ wv^T -> ov_stage
            const int c = w - 1;
            const int scb = 12288 + (w - 1) * 1536;
            f32x4 acc6[6] = {};
            #pragma unroll
            for (int kt = 0; kt < 4; kt++) {
                uint2 sid8 = *(const uint2*)&segid_s[kt*32 + 8*lg];
                s16x8 rv8 = *(const s16x8*)&rvb_s[c*128 + kt*32 + 8*lg];
                s16x8 af;
                #pragma unroll
                for (int j = 0; j < 8; j++) {
                    unsigned word = (j < 4) ? sid8.x : sid8.y;
                    int sid = (word >> (8 * (j & 3))) & 255;
                    af[j] = (sid == target) ? rv8[j] : (short)0;
                }
                #pragma unroll
                for (int nt = 0; nt < 6; nt++) {
                    s16x8 B = *(const s16x8*)&h_s[(kt*6 + nt) * 512 + l * 8];
                    acc6[nt] = __builtin_amdgcn_mfma_f32_16x16x32_bf16(af, B, acc6[nt], 0, 0, 0);
                }
            }
            #pragma unroll
            for (int nt = 0; nt < 6; nt++) {
                int ktf = nt >> 1;
                int lane2 = ((nt & 1) * 2 + (lr >> 3)) * 16 + 4*lg;
                int a0 = scb + ktf*512 + lane2*8 + (lr & 7);
                h_s[a0]      = f2bf(acc6[nt][0]);
                h_s[a0 + 8]  = f2bf(acc6[nt][1]);
                h_s[a0 + 16] = f2bf(acc6[nt][2]);
                h_s[a0 + 24] = f2bf(acc6[nt][3]);
            }
            s16x8 As[3];
            #pragma unroll
            for (int ktf = 0; ktf < 3; ktf++)
                As[ktf] = *(const s16x8*)&h_s[scb + ktf*512 + l*8];
            f32x4 acc2[4] = {};
            #pragma unroll
            for (int vt = 0; vt < 4; vt++)
            #pragma unroll
            for (int ktf = 0; ktf < 3; ktf++) {
                s16x8 B = *(const s16x8*)&wp[30720 + (ktf*4 + vt) * 512 + l * 8];
                acc2[vt] = __builtin_amdgcn_mfma_f32_16x16x32_bf16(As[ktf], B, acc2[vt], 0, 0, 0);
            }
            // stash into final [seg][v][c] layout (LDS scatter is cheap)
            #pragma unroll
            for (int vt = 0; vt < 4; vt++)
            #pragma unroll
            for (int j = 0; j < 4; j++)
                ov_stage[(4*lg + j) * 192 + (vt*16 + lr)*3 + c] = acc2[vt][j];
        }
        __syncthreads();   // ov_stage complete for this 16-seg tile
        // ---- cooperative contiguous flush: 48 float4 per segment
        int nloc = nseg - st*16; if (nloc > 16) nloc = 16;
        for (int f4 = tid; f4 < nloc * 48; f4 += 256) {
            int sl = f4 / 48;
            int off = (f4 - sl * 48) * 4;
            int g = st*16 + sl;
            int node = segnode_s[g];
            if (node >= 0) {
                f32x4 v = *(const f32x4*)&ov_stage[sl * 192 + off];
                float* p = &Ov[node*192 + off];
                if (g == 0 || g == nseg - 1) {
                    unsafeAtomicAdd(p+0, v[0]); unsafeAtomicAdd(p+1, v[1]);
                    unsafeAtomicAdd(p+2, v[2]); unsafeAtomicAdd(p+3, v[3]);
                } else {
                    __builtin_nontemporal_store(v, (f32x4*)p);
                }
            }
        }
        __syncthreads();   // before ov_stage reuse in next st tile
    }
}

extern "C" void kernel_launch(void* const* d_in, const int* in_sizes, int n_in,
                              void* d_out, int out_size, void* d_ws, size_t ws_size,
                              hipStream_t stream)
{
    const float* r_ij = (const float*)d_in[0];
    const float* w0   = (const float*)d_in[1];
    const float* b0   = (const float*)d_in[2];
    const float* w1   = (const float*)d_in[3];
    const float* b1   = (const float*)d_in[4];
    const float* w2   = (const float*)d_in[5];
    const float* b2   = (const float*)d_in[6];
    const float* w3   = (const float*)d_in[7];
    const float* wv   = (const float*)d_in[8];
    const int*   src  = (const int*)d_in[9];
    const int E = in_sizes[0] / 3;
    const int N = out_size / 288;
    float* A_a = (float*)d_out;
    float* Ov  = A_a + (size_t)N * 96;

    char* wsb = (char*)d_ws;
    unsigned short* wp = (unsigned short*)wsb;                  // 73728 B
    size_t off = 73728;
    int* counts = (int*)(wsb + off);  off += (((size_t)N*4 + 127) & ~127ull);
    int* cursor = (int*)(wsb + off);  off += (((size_t)N*4 + 127) & ~127ull);
    int* bsum   = (int*)(wsb + off);  off += 1024;
    size_t need_rsrt = off + (size_t)E * 16;
    int use_rsrt = (need_rsrt <= ws_size) ? 1 : 0;
    float4* rsrt = (float4*)(wsb + off);
    int* order   = (int*)(wsb + off);
    int* srcs    = (int*)(wsb + off + (((size_t)E*4 + 127) & ~127ull));

    const int nb = (N + 2047) / 2048;
    const long nz = (long)out_size / 4;     // out_size = 288*N, divisible by 4

    pack_weights_k<<<(PACK_TOT + 255) / 256, 256, 0, stream>>>(w0, w1, w2, w3, wv, wp,
                                                               counts, N);
    hist_k<<<(E + 255) / 256, 256, 0, stream>>>(src, counts, (float4*)d_out, nz, E);
    scan1_k<<<nb, 256, 0, stream>>>(counts, cursor, bsum, N);
    scatter_k<<<(E + 255) / 256, 256, 0, stream>>>(src, r_ij, bsum, cursor,
                                                   order, srcs, rsrt, use_rsrt, nb, E);
    edge_kernel<<<(E + 127) / 128, 256, 0, stream>>>(r_ij, order, srcs, rsrt, use_rsrt,
                                                     wp, b0, b1, b2, A_a, Ov, E);
}